// Round 7
// baseline (349.002 us; speedup 1.0000x reference)
//
#include <hip/hip_runtime.h>
#include <hip/hip_bf16.h>

#define HW 65536
#define KPAD 584   // Vt row stride (bf16): 1168B rows, 16B-aligned

typedef __attribute__((ext_vector_type(8))) short bf8;
typedef __attribute__((ext_vector_type(4))) float f4;

__device__ __forceinline__ unsigned short f2b(float x) {   // RNE float->bf16
  unsigned int u = __float_as_uint(x);
  unsigned int r = (u + 0x7fff + ((u >> 16) & 1)) >> 16;
  return (unsigned short)r;
}
__device__ __forceinline__ unsigned int pk2(float lo, float hi) {  // trunc pack 2xbf16
  return (__float_as_uint(hi) & 0xffff0000u) | (__float_as_uint(lo) >> 16);
}
__device__ __forceinline__ unsigned int pkrne(float lo, float hi) { // RNE pack 2xbf16
  return ((unsigned int)f2b(hi) << 16) | (unsigned int)f2b(lo);
}
__device__ __forceinline__ float blo(unsigned int u) { return __uint_as_float(u << 16); }
__device__ __forceinline__ float bhi(unsigned int u) { return __uint_as_float(u & 0xffff0000u); }
__device__ __forceinline__ float ex2(float x) { return __builtin_amdgcn_exp2f(x); }

// ================= device bodies =================
__device__ __forceinline__ void stem_front_body(
    int bx, int t, const float* __restrict__ depth,
    const float* __restrict__ cw1, const float* __restrict__ cb1,
    const float* __restrict__ cw2, const float* __restrict__ cb2,
    float* __restrict__ t2) {
  int p = bx * 256 + t;
  int y = p >> 8, x = p & 255;
  float in9[9];
#pragma unroll
  for (int ky = 0; ky < 3; ky++)
#pragma unroll
    for (int kx = 0; kx < 3; kx++) {
      int yy = y + ky - 1, xx = x + kx - 1;
      bool ok = ((unsigned)yy < 256u) && ((unsigned)xx < 256u);
      in9[ky*3+kx] = ok ? depth[yy*256+xx] : 0.f;
    }
  float t1[8];
#pragma unroll
  for (int o = 0; o < 8; o++) {
    float s = cb1[o];
#pragma unroll
    for (int i = 0; i < 9; i++) s += in9[i] * cw1[o*9+i];
    t1[o] = fmaxf(s, 0.f);
  }
#pragma unroll
  for (int o = 0; o < 16; o++) {
    float s = cb2[o];
#pragma unroll
    for (int ci = 0; ci < 8; ci++) s += t1[ci] * cw2[o*8+ci];
    t2[o*HW + p] = fmaxf(s, 0.f);
  }
}

// packed bf16 bias: word(hd,qt,kt2,quad,q,r) = pack(hi=bias(key+16,q), lo=bias(key,q))
// key = kt2*32 + quad*4 + r ; scale 1/ln2, no -8 shift (cancels in softmax)
__device__ __forceinline__ void bias_pk_body(
    int bx, int t, const int* __restrict__ rpi,
    const float* __restrict__ rpb, unsigned int* __restrict__ biasPk) {
  int idx = bx*256 + t;        // 288*256 = 73728 exact
  int hd = idx / 36864;
  int rem = idx - hd*36864;
  int qt = rem / 4608;
  int r2 = rem - qt*4608;
  int kt2 = r2 >> 8;
  int w8 = r2 & 255;
  int quad = w8 >> 6, q = (w8 >> 2) & 15, r = w8 & 3;
  int klo = kt2*32 + quad*4 + r;
  int qq = qt*16 + q;
  float lo = rpb[rpi[qq*576 + klo]*2 + hd] * 1.44269504f;
  float hi = rpb[rpi[qq*576 + klo + 16]*2 + hd] * 1.44269504f;
  biasPk[idx] = pkrne(lo, hi);
}

// 48-output LN(+IN) matmul slab, bf16-packed LDS weights, PACKED bf16 outputs.
// q pre-scaled by 0.25/ln2 (RNE pack).
__device__ __forceinline__ void lnmm48_body(
    int role, int bx, int t,
    unsigned int* ws16, float* gs, float* bs, float* b2s, float* as_, float* bbs_,
    const float* __restrict__ x, const float* __restrict__ t4,
    const float* __restrict__ part,
    const float* __restrict__ ig, const float* __restrict__ ib,
    const float* __restrict__ n1g, const float* __restrict__ n1b,
    const float* __restrict__ wq, const float* __restrict__ bq,
    const float* __restrict__ wkv, const float* __restrict__ bkv,
    unsigned int* __restrict__ q1, unsigned int* __restrict__ kv1,
    unsigned int* __restrict__ q2, unsigned int* __restrict__ kv2) {
  const float QS = 0.360673503f;   // 0.25/ln2
  bool ain = role >= 2;
  int slice = role & 1;
  const float* src = ain ? t4 : x;
  unsigned int* dq  = ain ? q2 : q1;
  unsigned int* dkv = ain ? kv1 : kv2;
  // stage weights bf16-packed: ws16[c*24 + jw] = pack(w[c][2jw], w[c][2jw+1])
  for (int i = t; i < 768; i += 256) {
    int c = i / 24, jw = i - c*24;
    int j = jw*2;
    float a, b;
    if (slice) { a = wkv[c*64 + 16 + j]; b = wkv[c*64 + 16 + j + 1]; }
    else if (j < 32) { a = wq[c*32 + j]; b = wq[c*32 + j + 1]; }
    else { a = wkv[c*64 + (j - 32)]; b = wkv[c*64 + (j - 31)]; }
    ws16[i] = pkrne(a, b);
  }
  if (t < 48) b2s[t] = slice ? bkv[16 + t] : (t < 32 ? bq[t] : bkv[t - 32]);
  if (t < 32) {
    gs[t] = n1g[t]; bs[t] = n1b[t];
    if (ain) {
      float m = part[t] * (1.f/65536.f);
      float var = part[32+t] * (1.f/65536.f) - m*m;
      float a = rsqrtf(var + 1e-5f) * ig[t];
      as_[t] = a; bbs_[t] = ib[t] - m*a;
    }
  }
  __syncthreads();
  int p = bx*256 + t;
  float v[32]; float s = 0.f;
  if (ain) {
#pragma unroll
    for (int c = 0; c < 32; c++) { v[c] = src[c*HW+p]*as_[c] + bbs_[c]; s += v[c]; }
  } else {
#pragma unroll
    for (int c = 0; c < 32; c++) { v[c] = src[c*HW+p]; s += v[c]; }
  }
  float m = s * 0.03125f;
  float ss = 0.f;
#pragma unroll
  for (int c = 0; c < 32; c++) { float d = v[c]-m; ss += d*d; }
  float rs = rsqrtf(ss*0.03125f + 1e-5f);
  float acc[48];
#pragma unroll
  for (int j = 0; j < 48; j++) acc[j] = b2s[j];
#pragma unroll
  for (int c = 0; c < 32; c++) {
    float ln = (v[c]-m)*rs*gs[c] + bs[c];
    const uint4* w4 = (const uint4*)&ws16[c*24];
#pragma unroll
    for (int q4 = 0; q4 < 6; q4++) {
      uint4 w = w4[q4];
      acc[q4*8+0] += ln*blo(w.x); acc[q4*8+1] += ln*bhi(w.x);
      acc[q4*8+2] += ln*blo(w.y); acc[q4*8+3] += ln*bhi(w.y);
      acc[q4*8+4] += ln*blo(w.z); acc[q4*8+5] += ln*bhi(w.z);
      acc[q4*8+6] += ln*blo(w.w); acc[q4*8+7] += ln*bhi(w.w);
    }
  }
  if (slice == 0) {
#pragma unroll
    for (int j2 = 0; j2 < 16; j2++)
      dq[j2*HW+p] = pkrne(acc[2*j2]*QS, acc[2*j2+1]*QS);
#pragma unroll
    for (int c2 = 0; c2 < 8; c2++)
      dkv[c2*HW+p] = pkrne(acc[32+2*c2], acc[32+2*c2+1]);
  } else {
#pragma unroll
    for (int c2 = 0; c2 < 24; c2++)
      dkv[(8+c2)*HW+p] = pkrne(acc[2*c2], acc[2*c2+1]);
  }
}

// ================= kernels =================
// flat mega-launch: [0,256) stem | [256,544) biasPk | [544,1056) lnmm48 roles 0,1
__global__ __launch_bounds__(256) void k_misc(
    const float* __restrict__ depth,
    const float* __restrict__ cw1, const float* __restrict__ cb1,
    const float* __restrict__ cw2, const float* __restrict__ cb2,
    float* __restrict__ t2,
    const int* __restrict__ rpi, const float* __restrict__ rpb,
    unsigned int* __restrict__ biasPk, float* __restrict__ part,
    const float* __restrict__ x, const float* __restrict__ t4,
    const float* __restrict__ ig, const float* __restrict__ ib,
    const float* __restrict__ n1g, const float* __restrict__ n1b,
    const float* __restrict__ wq, const float* __restrict__ bq,
    const float* __restrict__ wkv, const float* __restrict__ bkv,
    unsigned int* q1, unsigned int* kv1, unsigned int* q2, unsigned int* kv2) {
  __shared__ __align__(16) unsigned int ws16[768];
  __shared__ float gs[32], bs[32], b2s[48], as_[32], bbs_[32];
  int id = blockIdx.x, t = threadIdx.x;
  if (id < 256) { stem_front_body(id, t, depth, cw1, cb1, cw2, cb2, t2); return; }
  if (id < 544) {
    if (id == 256 && t < 64) part[t] = 0.f;   // zero IN-stat accumulators for k_conv4
    bias_pk_body(id - 256, t, rpi, rpb, biasPk);
    return;
  }
  int r = id - 544;
  lnmm48_body(r >> 8, r & 255, t, ws16, gs, bs, b2s, as_, bbs_,
              x, t4, part, ig, ib, n1g, n1b, wq, bq, wkv, bkv, q1, kv1, q2, kv2);
}

__global__ __launch_bounds__(256) void k_lnmmB(
    const float* __restrict__ x, const float* __restrict__ t4,
    const float* __restrict__ part,
    const float* __restrict__ ig, const float* __restrict__ ib,
    const float* __restrict__ n1g, const float* __restrict__ n1b,
    const float* __restrict__ wq, const float* __restrict__ bq,
    const float* __restrict__ wkv, const float* __restrict__ bkv,
    unsigned int* q1, unsigned int* kv1, unsigned int* q2, unsigned int* kv2) {
  __shared__ __align__(16) unsigned int ws16[768];
  __shared__ float gs[32], bs[32], b2s[48], as_[32], bbs_[32];
  lnmm48_body(2 + blockIdx.y, blockIdx.x, threadIdx.x, ws16, gs, bs, b2s, as_, bbs_,
              x, t4, part, ig, ib, n1g, n1b, wq, bq, wkv, bkv, q1, kv1, q2, kv2);
}

__global__ __launch_bounds__(256) void k_conv3(
    const float* __restrict__ t2, const float* __restrict__ cw3,
    const float* __restrict__ cb3, float* __restrict__ t3) {
  int t = threadIdx.x;
  int p = blockIdx.x*256 + t;
  int og = blockIdx.y;
  int y = p >> 8, x = p & 255;
  float acc[4];
#pragma unroll
  for (int o = 0; o < 4; o++) acc[o] = cb3[og*4+o];
#pragma unroll 1
  for (int tap = 0; tap < 9; tap++) {
    int ky = tap/3 - 1, kx = tap - (tap/3)*3 - 1;
    int yy = y+ky, xx = x+kx;
    bool ok = ((unsigned)yy < 256u) && ((unsigned)xx < 256u);
    int pp = yy*256+xx;
#pragma unroll
    for (int ci = 0; ci < 16; ci++) {
      float v = ok ? t2[ci*HW+pp] : 0.f;
#pragma unroll
      for (int o = 0; o < 4; o++)
        acc[o] += v * cw3[(og*4+o)*144 + ci*9 + tap];
    }
  }
#pragma unroll
  for (int o = 0; o < 4; o++) t3[(og*4+o)*HW+p] = fmaxf(acc[o], 0.f);
}

// conv4 + fused IN-stat partials (atomicAdd into part[ch]/part[32+ch])
__global__ __launch_bounds__(256) void k_conv4(
    const float* __restrict__ t3, const float* __restrict__ cw4,
    const float* __restrict__ cb4, float* __restrict__ t4,
    float* __restrict__ part) {
  int t = threadIdx.x;
  int p = blockIdx.x*256 + t;
  int og = blockIdx.y;           // 8 outputs per group
  float v[16];
#pragma unroll
  for (int ci = 0; ci < 16; ci++) v[ci] = t3[ci*HW+p];
  float s8[8], q8[8];
#pragma unroll
  for (int o = 0; o < 8; o++) {
    int oo = og*8 + o;
    float s = cb4[oo];
#pragma unroll
    for (int ci = 0; ci < 16; ci++) s += v[ci]*cw4[oo*16+ci];
    t4[oo*HW+p] = s;
    s8[o] = s; q8[o] = s*s;
  }
  // wave butterfly reduce (16 values x 6 steps)
#pragma unroll
  for (int off = 1; off < 64; off <<= 1) {
#pragma unroll
    for (int o = 0; o < 8; o++) {
      s8[o] += __shfl_xor(s8[o], off, 64);
      q8[o] += __shfl_xor(q8[o], off, 64);
    }
  }
  __shared__ float red[4][16];
  int wid = t >> 6, lane = t & 63;
  if (lane == 0) {
#pragma unroll
    for (int o = 0; o < 8; o++) { red[wid][o] = s8[o]; red[wid][8+o] = q8[o]; }
  }
  __syncthreads();
  if (t < 16) {
    float acc = red[0][t] + red[1][t] + red[2][t] + red[3][t];
    int o = t & 7;
    atomicAdd(&part[(t < 8 ? 0 : 32) + og*8 + o], acc);
  }
}

// ---------------- MFMA attention: bf16 bias, MFMA-summed denominator ----------------
__global__ __launch_bounds__(256, 4) void k_attn(
    const unsigned int* __restrict__ qA, const unsigned int* __restrict__ kvA,
    float* __restrict__ aoA,
    const unsigned int* __restrict__ qB, const unsigned int* __restrict__ kvB,
    float* __restrict__ aoB,
    const unsigned int* __restrict__ biasPk) {
  __shared__ __align__(16) unsigned short Ks[576*16];   // [key][d]  18432B
  __shared__ __align__(16) unsigned short Vt[16*KPAD];  // [d][key-permuted] 18688B

  const unsigned int* q  = blockIdx.y ? qB  : qA;
  const unsigned int* kv = blockIdx.y ? kvB : kvA;
  float* ao              = blockIdx.y ? aoB : aoA;

  // XCD swizzle: contiguous window stripes per XCD for kv-overlap L2 reuse
  int id = blockIdx.x;                       // 0..511
  int lin = ((id & 7) << 6) | (id >> 3);
  int wi = lin >> 1, hd = lin & 1;
  int wy = wi >> 4, wx = wi & 15;
  int t = threadIdx.x;
  int by = wy*16 - 4, bx = wx*16 - 4;
  int krow = hd*8, vrow = 16 + hd*8;         // packed word-row bases

  int wave = t >> 6, lane = t & 63;
  int quad = lane >> 4, l16 = lane & 15;
  const bf8 zero8 = {0,0,0,0,0,0,0,0};
  const bf8 ones8 = {0x3F80,0x3F80,0x3F80,0x3F80,0x3F80,0x3F80,0x3F80,0x3F80};

  // --- Q fragments: 4 packed dword loads each (pre-scaled bf16 in memory)
  bf8 qf[4];
#pragma unroll
  for (int qi = 0; qi < 4; qi++) {
    if (quad < 2) {
      int qt = wave*4 + qi;
      int prow = (wy*16 + qt)*256 + wx*16 + l16;
      union { unsigned int u[4]; bf8 v; } Q;
#pragma unroll
      for (int jw = 0; jw < 4; jw++)
        Q.u[jw] = q[(krow + quad*4 + jw)*HW + prow];
      qf[qi] = Q.v;
    } else {
      qf[qi] = zero8;
    }
  }

  // --- stage K (row-major) and V (transposed, slot-permuted)
  for (int e = t; e < 576; e += 256) {
    int dy = e / 24, dx = e - dy*24;
    int yy = by + dy, xx = bx + dx;
    bool ok = ((unsigned)yy < 256u) && ((unsigned)xx < 256u);
    int pp = yy*256 + xx;
    int off = e & 31;
    int ppos = ((off & 12) << 1) + ((off >> 4) << 2) + (off & 3);
    int vcol = (e & ~31) + ppos;
    unsigned int kwd[8];
#pragma unroll
    for (int i = 0; i < 8; i++) kwd[i] = ok ? kv[(krow + i)*HW + pp] : 0u;
    *(uint4*)&Ks[e*16]     = *(const uint4*)&kwd[0];
    *(uint4*)&Ks[e*16 + 8] = *(const uint4*)&kwd[4];
#pragma unroll
    for (int i = 0; i < 8; i++) {
      unsigned int vw = ok ? kv[(vrow + i)*HW + pp] : 0u;
      Vt[(2*i)*KPAD + vcol]   = (unsigned short)vw;
      Vt[(2*i+1)*KPAD + vcol] = (unsigned short)(vw >> 16);
    }
  }
  __syncthreads();

  f4 oacc[4];
  f4 lacc[4];
#pragma unroll
  for (int qi = 0; qi < 4; qi++) {
    oacc[qi] = (f4){0.f,0.f,0.f,0.f};
    lacc[qi] = (f4){0.f,0.f,0.f,0.f};
  }
  unsigned int bb0 = (unsigned)((hd*8 + wave*4)*4608 + quad*64 + l16*4);

#pragma unroll 2
  for (int kt2 = 0; kt2 < 18; kt2++) {
    int k0 = kt2 * 32;
    bf8 kf0 = zero8, kf1 = zero8;
    if (quad < 2) {
      kf0 = *(const bf8*)&Ks[(k0 + l16)*16 + quad*8];
      kf1 = *(const bf8*)&Ks[(k0 + 16 + l16)*16 + quad*8];
    }
    bf8 vf = *(const bf8*)&Vt[l16*KPAD + k0 + quad*8];
    __builtin_amdgcn_s_setprio(1);
#pragma unroll
    for (int qi = 0; qi < 4; qi++) {
      uint4 bw = *(const uint4*)&biasPk[bb0 + qi*4608 + kt2*256];
      f4 b0, b1;
      b0[0] = blo(bw.x); b1[0] = bhi(bw.x);
      b0[1] = blo(bw.y); b1[1] = bhi(bw.y);
      b0[2] = blo(bw.z); b1[2] = bhi(bw.z);
      b0[3] = blo(bw.w); b1[3] = bhi(bw.w);
      f4 s0 = __builtin_amdgcn_mfma_f32_16x16x32_bf16(kf0, qf[qi], b0, 0, 0, 0);
      f4 s1 = __builtin_amdgcn_mfma_f32_16x16x32_bf16(kf1, qf[qi], b1, 0, 0, 0);
      float p0[4], p1[4];
#pragma unroll
      for (int r = 0; r < 4; r++) {
        p0[r] = ex2(s0[r]);
        p1[r] = ex2(s1[r]);
      }
      union { unsigned int u[4]; bf8 v; } P;
      P.u[0] = pk2(p0[0], p0[1]); P.u[1] = pk2(p0[2], p0[3]);
      P.u[2] = pk2(p1[0], p1[1]); P.u[3] = pk2(p1[2], p1[3]);
      oacc[qi] = __builtin_amdgcn_mfma_f32_16x16x32_bf16(P.v, vf, oacc[qi], 0, 0, 0);
      lacc[qi] = __builtin_amdgcn_mfma_f32_16x16x32_bf16(P.v, ones8, lacc[qi], 0, 0, 0);
    }
    __builtin_amdgcn_s_setprio(0);
  }
#pragma unroll
  for (int qi = 0; qi < 4; qi++) {
    int qt = wave*4 + qi;
#pragma unroll
    for (int r = 0; r < 4; r++) {
      int qw = qt*16 + quad*4 + r;
      ao[(hd*16 + l16)*HW + (wy*16 + (qw >> 4))*256 + wx*16 + (qw & 15)] =
          oacc[qi][r] / lacc[qi][r];
    }
  }
}

// ---- merged proj+LN+MLP+final, lane-pair channel-split: lanes 2i/2i+1 share pixel ----
__global__ __launch_bounds__(256) void k_projmlp(
    const float* __restrict__ ao1, const float* __restrict__ ao2,
    const float* __restrict__ x, const float* __restrict__ t4,
    const float* __restrict__ part,
    const float* __restrict__ ig, const float* __restrict__ ib,
    const float* __restrict__ wp, const float* __restrict__ bp,
    const float* __restrict__ n2g, const float* __restrict__ n2b,
    const float* __restrict__ mw1, const float* __restrict__ mb1,
    const float* __restrict__ mw2, const float* __restrict__ mb2,
    float* __restrict__ out) {
  __shared__ __align__(16) float wps[1024];
  __shared__ __align__(16) float w1s[2048];
  __shared__ __align__(16) float w2s[2048];
  __shared__ float bps[32], b1s[64], b2s[32], gs[32], bs[32], as_[32], bbs_[32];
  int t = threadIdx.x;
  for (int i = t; i < 1024; i += 256) wps[i] = wp[i];
  for (int i = t; i < 2048; i += 256) { w1s[i] = mw1[i]; w2s[i] = mw2[i]; }
  if (t < 64) b1s[t] = mb1[t];
  if (t < 32) {
    bps[t] = bp[t]; b2s[t] = mb2[t]; gs[t] = n2g[t]; bs[t] = n2b[t];
    float m = part[t] * (1.f/65536.f);
    float var = part[32+t] * (1.f/65536.f) - m*m;
    float a = rsqrtf(var + 1e-5f) * ig[t];
    as_[t] = a; bbs_[t] = ib[t] - m*a;
  }
  __syncthreads();
  int p  = blockIdx.x*128 + (t >> 1);
  int sg = t & 1;           // channel-half owner
  int jb = sg*16;           // own output-channel base

  // --- proj both streams for own 16 channels (shared wp reads)
  float A[16], B[16];
#pragma unroll
  for (int jj = 0; jj < 16; jj++) { A[jj] = bps[jb+jj]; B[jj] = A[jj]; }
#pragma unroll
  for (int c = 0; c < 32; c++) {
    float va = ao1[c*HW+p];
    float vb = ao2[c*HW+p];
    const float4* w4 = (const float4*)&wps[c*32 + jb];
#pragma unroll
    for (int j4 = 0; j4 < 4; j4++) {
      float4 w = w4[j4];
      A[j4*4+0] += va*w.x; A[j4*4+1] += va*w.y; A[j4*4+2] += va*w.z; A[j4*4+3] += va*w.w;
      B[j4*4+0] += vb*w.x; B[j4*4+1] += vb*w.y; B[j4*4+2] += vb*w.z; B[j4*4+3] += vb*w.w;
    }
  }
  // --- shortcuts + OUT init (own channels)
  float OUT[16];
#pragma unroll
  for (int jj = 0; jj < 16; jj++) {
    float xv = x[(jb+jj)*HW+p];
    float tv = t4[(jb+jj)*HW+p]*as_[jb+jj] + bbs_[jb+jj];
    A[jj] += xv; B[jj] += tv;
    OUT[jj] = A[jj] + B[jj] + xv + 2.f*b2s[jb+jj];
  }
  // --- LN stats via lane-pair reduce
  float sA = 0.f, sB = 0.f;
#pragma unroll
  for (int jj = 0; jj < 16; jj++) { sA += A[jj]; sB += B[jj]; }
  sA += __shfl_xor(sA, 1, 64);
  sB += __shfl_xor(sB, 1, 64);
  float mA = sA * 0.03125f, mB = sB * 0.03125f;
  float ssA = 0.f, ssB = 0.f;
#pragma unroll
  for (int jj = 0; jj < 16; jj++) {
    float dA = A[jj]-mA, dB = B[jj]-mB;
    ssA += dA*dA; ssB += dB*dB;
  }
  ssA += __shfl_xor(ssA, 1, 64);
  ssB += __shfl_xor(ssB, 1, 64);
  float rsA = rsqrtf(ssA*0.03125f + 1e-5f);
  float rsB = rsqrtf(ssB*0.03125f + 1e-5f);
  // --- ln own + pair exchange -> full 32 per stream (static-indexed halves)
  float lnA_lo[16], lnA_hi[16], lnB_lo[16], lnB_hi[16];
#pragma unroll
  for (int jj = 0; jj < 16; jj++) {
    float ownA = (A[jj]-mA)*rsA*gs[jb+jj] + bs[jb+jj];
    float ownB = (B[jj]-mB)*rsB*gs[jb+jj] + bs[jb+jj];
    float othA = __shfl_xor(ownA, 1, 64);
    float othB = __shfl_xor(ownB, 1, 64);
    lnA_lo[jj] = sg ? othA : ownA;
    lnA_hi[jj] = sg ? ownA : othA;
    lnB_lo[jj] = sg ? othB : ownB;
    lnB_hi[jj] = sg ? ownB : othB;
  }
  // --- mlp1: own 32 of 64 hidden (k = sg*32+kk), both streams share w1 reads
  float h0[32], h1[32];
#pragma unroll
  for (int kk = 0; kk < 32; kk++) { h0[kk] = b1s[sg*32+kk]; h1[kk] = h0[kk]; }
#pragma unroll
  for (int c = 0; c < 32; c++) {
    float l0 = (c < 16) ? lnA_lo[c] : lnA_hi[c-16];
    float l1 = (c < 16) ? lnB_lo[c] : lnB_hi[c-16];
    const float4* w4 = (const float4*)&w1s[c*64 + sg*32];
#pragma unroll
    for (int k4 = 0; k4 < 8; k4++) {
      float4 w = w4[k4];
      h0[k4*4+0] += l0*w.x; h0[k4*4+1] += l0*w.y; h0[k4*4+2] += l0*w.z; h0[k4*4+3] += l0*w.w;
      h1[k4*4+0] += l1*w.x; h1[k4*4+1] += l1*w.y; h1[k4*4+2] += l1*w.z; h1[k4*4+3] += l1*w.w;
    }
  }
  // --- gelu, then g = gelu(h0)+gelu(h1) (mlp2 is linear: r0+r1 = mlp2(g))
#pragma unroll
  for (int kk = 0; kk < 32; kk++) {
    float x0 = h0[kk], x1 = h1[kk];
    float u0 = 0.7978845608f * (x0 + 0.044715f*x0*x0*x0);
    float u1 = 0.7978845608f * (x1 + 0.044715f*x1*x1*x1);
    float th0 = 1.f - 2.f/(1.f + __expf(2.f*u0));
    float th1 = 1.f - 2.f/(1.f + __expf(2.f*u1));
    h0[kk] = 0.5f*x0*(1.f + th0) + 0.5f*x1*(1.f + th1);
  }
  // --- mlp2 partials over own k-half, for ALL 32 j (two static halves)
  float plo[16], phi[16];
#pragma unroll
  for (int jj = 0; jj < 16; jj++) { plo[jj] = 0.f; phi[jj] = 0.f; }
#pragma unroll
  for (int kk = 0; kk < 32; kk++) {
    float gk = h0[kk];
    const float4* w4 = (const float4*)&w2s[(sg*32+kk)*32];
#pragma unroll
    for (int j4 = 0; j4 < 4; j4++) {
      float4 w = w4[j4];
      plo[j4*4+0] += gk*w.x; plo[j4*4+1] += gk*w.y;
      plo[j4*4+2] += gk*w.z; plo[j4*4+3] += gk*w.w;
    }
#pragma unroll
    for (int j4 = 0; j4 < 4; j4++) {
      float4 w = w4[4+j4];
      phi[j4*4+0] += gk*w.x; phi[j4*4+1] += gk*w.y;
      phi[j4*4+2] += gk*w.z; phi[j4*4+3] += gk*w.w;
    }
  }
  // --- pair exchange of cross-half partials, accumulate, store
#pragma unroll
  for (int jj = 0; jj < 16; jj++) {
    float send = sg ? plo[jj] : phi[jj];    // what partner needs
    float recv = __shfl_xor(send, 1, 64);   // partner's partial at my j
    float own  = sg ? phi[jj] : plo[jj];
    out[(jb+jj)*HW + p] = OUT[jj] + own + recv;
  }
}

extern "C" void kernel_launch(void* const* d_in, const int* in_sizes, int n_in,
                              void* d_out, int out_size, void* d_ws, size_t ws_size,
                              hipStream_t stream) {
  const float* x    = (const float*)d_in[0];
  const float* depth= (const float*)d_in[1];
  const int*   rpi  = (const int*)d_in[2];
  const float* cw1  = (const float*)d_in[3],  *cb1 = (const float*)d_in[4];
  const float* cw2  = (const float*)d_in[5],  *cb2 = (const float*)d_in[6];
  const float* cw3  = (const float*)d_in[7],  *cb3 = (const float*)d_in[8];
  const float* cw4  = (const float*)d_in[9],  *cb4 = (const float*)d_in[10];
  const float* in_g = (const float*)d_in[11], *in_b = (const float*)d_in[12];
  const float* n1g  = (const float*)d_in[13], *n1b = (const float*)d_in[14];
  const float* wq   = (const float*)d_in[15], *bq  = (const float*)d_in[16];
  const float* wkv  = (const float*)d_in[17], *bkv = (const float*)d_in[18];
  const float* rpb  = (const float*)d_in[19];
  const float* wp   = (const float*)d_in[20], *bp  = (const float*)d_in[21];
  const float* n2g  = (const float*)d_in[22], *n2b = (const float*)d_in[23];
  const float* mw1  = (const float*)d_in[24], *mb1 = (const float*)d_in[25];
  const float* mw2  = (const float*)d_in[26], *mb2 = (const float*)d_in[27];

  float* W   = (float*)d_ws;
  float* o1  = (float*)d_out;

  // workspace layout (floats), total < 51.5 MB
  float* t4    = W;                          // 2M
  unsigned int* q1  = (unsigned int*)(W + 2097152);   // 1M words
  unsigned int* q2  = (unsigned int*)(W + 3145728);   // 1M words
  unsigned int* kv1 = (unsigned int*)(W + 4194304);   // 2M words
  unsigned int* kv2 = (unsigned int*)(W + 6291456);   // 2M words
  float* ao1   = W + 8388608;                // 2M
  float* ao2   = W + 10485760;               // 2M
  unsigned int* biasPk = (unsigned int*)(W + 12582912);  // 73728 words
  float* part  = W + 12877824;               // 64 floats
  float* t2 = ao1;                           // 1M used, dead before attn writes ao1
  float* t3 = ao2;                           // 1M used, dead before attn writes ao2

  // flat misc: stem(256) + biasPk(288) + lnmm48 roles 0,1 (512) = 1056 blocks
  k_misc   <<<1056, 256, 0, stream>>>(depth, cw1, cb1, cw2, cb2, t2,
                                      rpi, rpb, biasPk, part,
                                      x, t4, in_g, in_b, n1g, n1b,
                                      wq, bq, wkv, bkv, q1, kv1, q2, kv2);
  k_conv3  <<<dim3(256,4), 256, 0, stream>>>(t2, cw3, cb3, t3);
  k_conv4  <<<dim3(256,4), 256, 0, stream>>>(t3, cw4, cb4, t4, part);
  // roles 2,3: src=IN(t4) -> q2, kv1
  k_lnmmB  <<<dim3(256,2), 256, 0, stream>>>(x, t4, part, in_g, in_b, n1g, n1b,
                                             wq, bq, wkv, bkv, q1, kv1, q2, kv2);
  k_attn   <<<dim3(512,2), 256, 0, stream>>>(q1, kv1, ao1, q2, kv2, ao2, biasPk);
  k_projmlp<<<512, 256, 0, stream>>>(ao1, ao2, x, t4, part, in_g, in_b,
                                     wp, bp, n2g, n2b, mw1, mb1, mw2, mb2, o1);
}

// Round 8
// 237.041 us; speedup vs baseline: 1.4723x; 1.4723x over previous
//
#include <hip/hip_runtime.h>
#include <hip/hip_bf16.h>

#define HW 65536
#define KPAD 584   // Vt row stride (bf16): 1168B rows, 16B-aligned

typedef __attribute__((ext_vector_type(8))) short bf8;
typedef __attribute__((ext_vector_type(4))) float f4;

__device__ __forceinline__ unsigned short f2b(float x) {   // RNE float->bf16
  unsigned int u = __float_as_uint(x);
  unsigned int r = (u + 0x7fff + ((u >> 16) & 1)) >> 16;
  return (unsigned short)r;
}
__device__ __forceinline__ unsigned int pk2(float lo, float hi) {  // trunc pack 2xbf16
  return (__float_as_uint(hi) & 0xffff0000u) | (__float_as_uint(lo) >> 16);
}
__device__ __forceinline__ unsigned int pkrne(float lo, float hi) { // RNE pack 2xbf16
  return ((unsigned int)f2b(hi) << 16) | (unsigned int)f2b(lo);
}
__device__ __forceinline__ float blo(unsigned int u) { return __uint_as_float(u << 16); }
__device__ __forceinline__ float bhi(unsigned int u) { return __uint_as_float(u & 0xffff0000u); }
__device__ __forceinline__ float ex2(float x) { return __builtin_amdgcn_exp2f(x); }

// ================= device bodies =================
__device__ __forceinline__ void stem_front_body(
    int bx, int t, const float* __restrict__ depth,
    const float* __restrict__ cw1, const float* __restrict__ cb1,
    const float* __restrict__ cw2, const float* __restrict__ cb2,
    float* __restrict__ t2) {
  int p = bx * 256 + t;
  int y = p >> 8, x = p & 255;
  float in9[9];
#pragma unroll
  for (int ky = 0; ky < 3; ky++)
#pragma unroll
    for (int kx = 0; kx < 3; kx++) {
      int yy = y + ky - 1, xx = x + kx - 1;
      bool ok = ((unsigned)yy < 256u) && ((unsigned)xx < 256u);
      in9[ky*3+kx] = ok ? depth[yy*256+xx] : 0.f;
    }
  float t1[8];
#pragma unroll
  for (int o = 0; o < 8; o++) {
    float s = cb1[o];
#pragma unroll
    for (int i = 0; i < 9; i++) s += in9[i] * cw1[o*9+i];
    t1[o] = fmaxf(s, 0.f);
  }
#pragma unroll
  for (int o = 0; o < 16; o++) {
    float s = cb2[o];
#pragma unroll
    for (int ci = 0; ci < 8; ci++) s += t1[ci] * cw2[o*8+ci];
    t2[o*HW + p] = fmaxf(s, 0.f);
  }
}

// FULL packed bf16 bias table: 2 hd x 16 qt x 18 kt2 x 256 = 147456 words.
// word((hd*16+qt)*4608 + kt2*256 + quad*64 + q16*4 + r)
//   = pack(lo=bias(key,qq), hi=bias(key+16,qq)), key = kt2*32+quad*4+r, qq = qt*16+q16
// scale 1/ln2, NO -8 shift (cancels between oacc and lacc; bf16 stores ~0.04 exactly)
__device__ __forceinline__ void bias_pk_body(
    int bx, int t, const int* __restrict__ rpi,
    const float* __restrict__ rpb, unsigned int* __restrict__ biasPk) {
  int idx = bx*256 + t;        // 576*256 = 147456 exact
  int hd = idx / 73728;
  int rem = idx - hd*73728;
  int qt = rem / 4608;         // [0,16)
  int r2 = rem - qt*4608;
  int kt2 = r2 >> 8;           // [0,18)
  int w8 = r2 & 255;
  int quad = w8 >> 6, q16 = (w8 >> 2) & 15, r = w8 & 3;
  int klo = kt2*32 + quad*4 + r;
  int qq = qt*16 + q16;
  float lo = rpb[rpi[qq*576 + klo]*2 + hd] * 1.44269504f;
  float hi = rpb[rpi[qq*576 + klo + 16]*2 + hd] * 1.44269504f;
  biasPk[idx] = pkrne(lo, hi);
}

// 48-output LN(+IN) matmul slab, bf16-packed LDS weights, PACKED bf16 outputs.
// q pre-scaled by 0.25/ln2 (RNE pack).
__device__ __forceinline__ void lnmm48_body(
    int role, int bx, int t,
    unsigned int* ws16, float* gs, float* bs, float* b2s, float* as_, float* bbs_,
    const float* __restrict__ x, const float* __restrict__ t4,
    const float* __restrict__ part,
    const float* __restrict__ ig, const float* __restrict__ ib,
    const float* __restrict__ n1g, const float* __restrict__ n1b,
    const float* __restrict__ wq, const float* __restrict__ bq,
    const float* __restrict__ wkv, const float* __restrict__ bkv,
    unsigned int* __restrict__ q1, unsigned int* __restrict__ kv1,
    unsigned int* __restrict__ q2, unsigned int* __restrict__ kv2) {
  const float QS = 0.360673503f;   // 0.25/ln2
  bool ain = role >= 2;
  int slice = role & 1;
  const float* src = ain ? t4 : x;
  unsigned int* dq  = ain ? q2 : q1;
  unsigned int* dkv = ain ? kv1 : kv2;
  // stage weights bf16-packed: ws16[c*24 + jw] = pack(w[c][2jw], w[c][2jw+1])
  for (int i = t; i < 768; i += 256) {
    int c = i / 24, jw = i - c*24;
    int j = jw*2;
    float a, b;
    if (slice) { a = wkv[c*64 + 16 + j]; b = wkv[c*64 + 16 + j + 1]; }
    else if (j < 32) { a = wq[c*32 + j]; b = wq[c*32 + j + 1]; }
    else { a = wkv[c*64 + (j - 32)]; b = wkv[c*64 + (j - 31)]; }
    ws16[i] = pkrne(a, b);
  }
  if (t < 48) b2s[t] = slice ? bkv[16 + t] : (t < 32 ? bq[t] : bkv[t - 32]);
  if (t < 32) {
    gs[t] = n1g[t]; bs[t] = n1b[t];
    if (ain) {
      float s = 0.f, ss = 0.f;
#pragma unroll
      for (int k = 0; k < 16; k++) { s += part[t*16+k]; ss += part[512 + t*16+k]; }
      float m = s * (1.f/65536.f);
      float var = ss * (1.f/65536.f) - m*m;
      float a = rsqrtf(var + 1e-5f) * ig[t];
      as_[t] = a; bbs_[t] = ib[t] - m*a;
    }
  }
  __syncthreads();
  int p = bx*256 + t;
  float v[32]; float s = 0.f;
  if (ain) {
#pragma unroll
    for (int c = 0; c < 32; c++) { v[c] = src[c*HW+p]*as_[c] + bbs_[c]; s += v[c]; }
  } else {
#pragma unroll
    for (int c = 0; c < 32; c++) { v[c] = src[c*HW+p]; s += v[c]; }
  }
  float m = s * 0.03125f;
  float ss = 0.f;
#pragma unroll
  for (int c = 0; c < 32; c++) { float d = v[c]-m; ss += d*d; }
  float rs = rsqrtf(ss*0.03125f + 1e-5f);
  float acc[48];
#pragma unroll
  for (int j = 0; j < 48; j++) acc[j] = b2s[j];
#pragma unroll
  for (int c = 0; c < 32; c++) {
    float ln = (v[c]-m)*rs*gs[c] + bs[c];
    const uint4* w4 = (const uint4*)&ws16[c*24];
#pragma unroll
    for (int q4 = 0; q4 < 6; q4++) {
      uint4 w = w4[q4];
      acc[q4*8+0] += ln*blo(w.x); acc[q4*8+1] += ln*bhi(w.x);
      acc[q4*8+2] += ln*blo(w.y); acc[q4*8+3] += ln*bhi(w.y);
      acc[q4*8+4] += ln*blo(w.z); acc[q4*8+5] += ln*bhi(w.z);
      acc[q4*8+6] += ln*blo(w.w); acc[q4*8+7] += ln*bhi(w.w);
    }
  }
  if (slice == 0) {
#pragma unroll
    for (int j2 = 0; j2 < 16; j2++)
      dq[j2*HW+p] = pkrne(acc[2*j2]*QS, acc[2*j2+1]*QS);
#pragma unroll
    for (int c2 = 0; c2 < 8; c2++)
      dkv[c2*HW+p] = pkrne(acc[32+2*c2], acc[32+2*c2+1]);
  } else {
#pragma unroll
    for (int c2 = 0; c2 < 24; c2++)
      dkv[(8+c2)*HW+p] = pkrne(acc[2*c2], acc[2*c2+1]);
  }
}

// ================= kernels =================
// flat mega-launch: [0,256) stem | [256,832) biasPk | [832,1344) lnmm48 roles 0,1
__global__ __launch_bounds__(256) void k_misc(
    const float* __restrict__ depth,
    const float* __restrict__ cw1, const float* __restrict__ cb1,
    const float* __restrict__ cw2, const float* __restrict__ cb2,
    float* __restrict__ t2,
    const int* __restrict__ rpi, const float* __restrict__ rpb,
    unsigned int* __restrict__ biasPk,
    const float* __restrict__ x, const float* __restrict__ t4,
    const float* __restrict__ part,
    const float* __restrict__ ig, const float* __restrict__ ib,
    const float* __restrict__ n1g, const float* __restrict__ n1b,
    const float* __restrict__ wq, const float* __restrict__ bq,
    const float* __restrict__ wkv, const float* __restrict__ bkv,
    unsigned int* q1, unsigned int* kv1, unsigned int* q2, unsigned int* kv2) {
  __shared__ __align__(16) unsigned int ws16[768];
  __shared__ float gs[32], bs[32], b2s[48], as_[32], bbs_[32];
  int id = blockIdx.x, t = threadIdx.x;
  if (id < 256) { stem_front_body(id, t, depth, cw1, cb1, cw2, cb2, t2); return; }
  if (id < 832) { bias_pk_body(id - 256, t, rpi, rpb, biasPk); return; }
  int r = id - 832;
  lnmm48_body(r >> 8, r & 255, t, ws16, gs, bs, b2s, as_, bbs_,
              x, t4, part, ig, ib, n1g, n1b, wq, bq, wkv, bkv, q1, kv1, q2, kv2);
}

__global__ __launch_bounds__(256) void k_lnmmB(
    const float* __restrict__ x, const float* __restrict__ t4,
    const float* __restrict__ part,
    const float* __restrict__ ig, const float* __restrict__ ib,
    const float* __restrict__ n1g, const float* __restrict__ n1b,
    const float* __restrict__ wq, const float* __restrict__ bq,
    const float* __restrict__ wkv, const float* __restrict__ bkv,
    unsigned int* q1, unsigned int* kv1, unsigned int* q2, unsigned int* kv2) {
  __shared__ __align__(16) unsigned int ws16[768];
  __shared__ float gs[32], bs[32], b2s[48], as_[32], bbs_[32];
  lnmm48_body(2 + blockIdx.y, blockIdx.x, threadIdx.x, ws16, gs, bs, b2s, as_, bbs_,
              x, t4, part, ig, ib, n1g, n1b, wq, bq, wkv, bkv, q1, kv1, q2, kv2);
}

__global__ __launch_bounds__(256) void k_conv3(
    const float* __restrict__ t2, const float* __restrict__ cw3,
    const float* __restrict__ cb3, float* __restrict__ t3) {
  int t = threadIdx.x;
  int p = blockIdx.x*256 + t;
  int og = blockIdx.y;
  int y = p >> 8, x = p & 255;
  float acc[4];
#pragma unroll
  for (int o = 0; o < 4; o++) acc[o] = cb3[og*4+o];
#pragma unroll 1
  for (int tap = 0; tap < 9; tap++) {
    int ky = tap/3 - 1, kx = tap - (tap/3)*3 - 1;
    int yy = y+ky, xx = x+kx;
    bool ok = ((unsigned)yy < 256u) && ((unsigned)xx < 256u);
    int pp = yy*256+xx;
#pragma unroll
    for (int ci = 0; ci < 16; ci++) {
      float v = ok ? t2[ci*HW+pp] : 0.f;
#pragma unroll
      for (int o = 0; o < 4; o++)
        acc[o] += v * cw3[(og*4+o)*144 + ci*9 + tap];
    }
  }
#pragma unroll
  for (int o = 0; o < 4; o++) t3[(og*4+o)*HW+p] = fmaxf(acc[o], 0.f);
}

// conv4 split over y: 8 outputs per block -> 1024 blocks
__global__ __launch_bounds__(256) void k_conv4(
    const float* __restrict__ t3, const float* __restrict__ cw4,
    const float* __restrict__ cb4, float* __restrict__ t4) {
  int t = threadIdx.x;
  int p = blockIdx.x*256 + t;
  int og = blockIdx.y;           // 8 outputs per group
  float v[16];
#pragma unroll
  for (int ci = 0; ci < 16; ci++) v[ci] = t3[ci*HW+p];
#pragma unroll
  for (int o = 0; o < 8; o++) {
    int oo = og*8 + o;
    float s = cb4[oo];
#pragma unroll
    for (int ci = 0; ci < 16; ci++) s += v[ci]*cw4[oo*16+ci];
    t4[oo*HW+p] = s;
  }
}

__global__ __launch_bounds__(256) void k_instats1(const float* __restrict__ t4,
                                                  float* __restrict__ part) {
  int c = blockIdx.x >> 4, seg = blockIdx.x & 15;   // 512 blocks
  const float4* src = (const float4*)(t4 + c*HW + seg*4096);
  float s = 0.f, ss = 0.f;
  for (int i = threadIdx.x; i < 1024; i += 256) {
    float4 v = src[i];
    s  += v.x + v.y + v.z + v.w;
    ss += v.x*v.x + v.y*v.y + v.z*v.z + v.w*v.w;
  }
#pragma unroll
  for (int off = 32; off > 0; off >>= 1) {
    s  += __shfl_down(s, off, 64);
    ss += __shfl_down(ss, off, 64);
  }
  __shared__ float sh[8];
  int wid = threadIdx.x >> 6;
  if ((threadIdx.x & 63) == 0) { sh[wid] = s; sh[4+wid] = ss; }
  __syncthreads();
  if (threadIdx.x == 0) {
    part[blockIdx.x]       = sh[0]+sh[1]+sh[2]+sh[3];
    part[512 + blockIdx.x] = sh[4]+sh[5]+sh[6]+sh[7];
  }
}

// ---------------- MFMA attention: bf16-packed bias + MFMA denominator ----------------
__global__ __launch_bounds__(256, 4) void k_attn(
    const unsigned int* __restrict__ qA, const unsigned int* __restrict__ kvA,
    float* __restrict__ aoA,
    const unsigned int* __restrict__ qB, const unsigned int* __restrict__ kvB,
    float* __restrict__ aoB,
    const unsigned int* __restrict__ biasPk) {
  __shared__ __align__(16) unsigned short Ks[576*16];   // [key][d]  18432B
  __shared__ __align__(16) unsigned short Vt[16*KPAD];  // [d][key-permuted] 18688B

  const unsigned int* q  = blockIdx.y ? qB  : qA;
  const unsigned int* kv = blockIdx.y ? kvB : kvA;
  float* ao              = blockIdx.y ? aoB : aoA;

  // XCD swizzle: contiguous window stripes per XCD for kv-overlap L2 reuse
  int id = blockIdx.x;                       // 0..511
  int lin = ((id & 7) << 6) | (id >> 3);
  int wi = lin >> 1, hd = lin & 1;
  int wy = wi >> 4, wx = wi & 15;
  int t = threadIdx.x;
  int by = wy*16 - 4, bx = wx*16 - 4;
  int krow = hd*8, vrow = 16 + hd*8;         // packed word-row bases

  int wave = t >> 6, lane = t & 63;
  int quad = lane >> 4, l16 = lane & 15;
  const bf8 zero8 = {0,0,0,0,0,0,0,0};
  const bf8 ones8 = {0x3F80,0x3F80,0x3F80,0x3F80,0x3F80,0x3F80,0x3F80,0x3F80};

  // --- Q fragments: 4 packed dword loads each (pre-scaled bf16 in memory)
  bf8 qf[4];
#pragma unroll
  for (int qi = 0; qi < 4; qi++) {
    if (quad < 2) {
      int qt = wave*4 + qi;
      int prow = (wy*16 + qt)*256 + wx*16 + l16;
      union { unsigned int u[4]; bf8 v; } Q;
#pragma unroll
      for (int jw = 0; jw < 4; jw++)
        Q.u[jw] = q[(krow + quad*4 + jw)*HW + prow];
      qf[qi] = Q.v;
    } else {
      qf[qi] = zero8;
    }
  }

  // --- stage K (row-major) and V (transposed, slot-permuted)
  for (int e = t; e < 576; e += 256) {
    int dy = e / 24, dx = e - dy*24;
    int yy = by + dy, xx = bx + dx;
    bool ok = ((unsigned)yy < 256u) && ((unsigned)xx < 256u);
    int pp = yy*256 + xx;
    int off = e & 31;
    int ppos = ((off & 12) << 1) + ((off >> 4) << 2) + (off & 3);
    int vcol = (e & ~31) + ppos;
    unsigned int kwd[8];
#pragma unroll
    for (int i = 0; i < 8; i++) kwd[i] = ok ? kv[(krow + i)*HW + pp] : 0u;
    *(uint4*)&Ks[e*16]     = *(const uint4*)&kwd[0];
    *(uint4*)&Ks[e*16 + 8] = *(const uint4*)&kwd[4];
#pragma unroll
    for (int i = 0; i < 8; i++) {
      unsigned int vw = ok ? kv[(vrow + i)*HW + pp] : 0u;
      Vt[(2*i)*KPAD + vcol]   = (unsigned short)vw;
      Vt[(2*i+1)*KPAD + vcol] = (unsigned short)(vw >> 16);
    }
  }
  __syncthreads();

  f4 oacc[4];
  f4 lacc[4];
#pragma unroll
  for (int qi = 0; qi < 4; qi++) {
    oacc[qi] = (f4){0.f,0.f,0.f,0.f};
    lacc[qi] = (f4){0.f,0.f,0.f,0.f};
  }
  // full-table base: (hd*16 + qt)*4608 + kt2*256 + quad*64 + l16*4
  unsigned int bb0 = (unsigned)((hd*16 + wave*4)*4608 + quad*64 + l16*4);

#pragma unroll 2
  for (int kt2 = 0; kt2 < 18; kt2++) {
    int k0 = kt2 * 32;
    bf8 kf0 = zero8, kf1 = zero8;
    if (quad < 2) {
      kf0 = *(const bf8*)&Ks[(k0 + l16)*16 + quad*8];
      kf1 = *(const bf8*)&Ks[(k0 + 16 + l16)*16 + quad*8];
    }
    bf8 vf = *(const bf8*)&Vt[l16*KPAD + k0 + quad*8];
    __builtin_amdgcn_s_setprio(1);
#pragma unroll
    for (int qi = 0; qi < 4; qi++) {
      uint4 bw = *(const uint4*)&biasPk[bb0 + qi*4608 + kt2*256];
      f4 b0, b1;
      b0[0] = blo(bw.x); b1[0] = bhi(bw.x);
      b0[1] = blo(bw.y); b1[1] = bhi(bw.y);
      b0[2] = blo(bw.z); b1[2] = bhi(bw.z);
      b0[3] = blo(bw.w); b1[3] = bhi(bw.w);
      f4 s0 = __builtin_amdgcn_mfma_f32_16x16x32_bf16(kf0, qf[qi], b0, 0, 0, 0);
      f4 s1 = __builtin_amdgcn_mfma_f32_16x16x32_bf16(kf1, qf[qi], b1, 0, 0, 0);
      float p0[4], p1[4];
#pragma unroll
      for (int r = 0; r < 4; r++) {
        p0[r] = ex2(s0[r]);
        p1[r] = ex2(s1[r]);
      }
      union { unsigned int u[4]; bf8 v; } P;
      P.u[0] = pk2(p0[0], p0[1]); P.u[1] = pk2(p0[2], p0[3]);
      P.u[2] = pk2(p1[0], p1[1]); P.u[3] = pk2(p1[2], p1[3]);
      oacc[qi] = __builtin_amdgcn_mfma_f32_16x16x32_bf16(P.v, vf, oacc[qi], 0, 0, 0);
      lacc[qi] = __builtin_amdgcn_mfma_f32_16x16x32_bf16(P.v, ones8, lacc[qi], 0, 0, 0);
    }
    __builtin_amdgcn_s_setprio(0);
  }
#pragma unroll
  for (int qi = 0; qi < 4; qi++) {
    int qt = wave*4 + qi;
#pragma unroll
    for (int r = 0; r < 4; r++) {
      int qw = qt*16 + quad*4 + r;
      ao[(hd*16 + l16)*HW + (wy*16 + (qw >> 4))*256 + wx*16 + (qw & 15)] =
          oacc[qi][r] / lacc[qi][r];
    }
  }
}

// ---- merged proj+LN+MLP+final, lane-pair channel-split (round-6 verbatim) ----
__global__ __launch_bounds__(256) void k_projmlp(
    const float* __restrict__ ao1, const float* __restrict__ ao2,
    const float* __restrict__ x, const float* __restrict__ t4,
    const float* __restrict__ part,
    const float* __restrict__ ig, const float* __restrict__ ib,
    const float* __restrict__ wp, const float* __restrict__ bp,
    const float* __restrict__ n2g, const float* __restrict__ n2b,
    const float* __restrict__ mw1, const float* __restrict__ mb1,
    const float* __restrict__ mw2, const float* __restrict__ mb2,
    float* __restrict__ out) {
  __shared__ __align__(16) float wps[1024];
  __shared__ __align__(16) float w1s[2048];
  __shared__ __align__(16) float w2s[2048];
  __shared__ float bps[32], b1s[64], b2s[32], gs[32], bs[32], as_[32], bbs_[32];
  int t = threadIdx.x;
  for (int i = t; i < 1024; i += 256) wps[i] = wp[i];
  for (int i = t; i < 2048; i += 256) { w1s[i] = mw1[i]; w2s[i] = mw2[i]; }
  if (t < 64) b1s[t] = mb1[t];
  if (t < 32) {
    bps[t] = bp[t]; b2s[t] = mb2[t]; gs[t] = n2g[t]; bs[t] = n2b[t];
    float s = 0.f, ss = 0.f;
#pragma unroll
    for (int k = 0; k < 16; k++) { s += part[t*16+k]; ss += part[512 + t*16+k]; }
    float m = s * (1.f/65536.f);
    float var = ss * (1.f/65536.f) - m*m;
    float a = rsqrtf(var + 1e-5f) * ig[t];
    as_[t] = a; bbs_[t] = ib[t] - m*a;
  }
  __syncthreads();
  int p  = blockIdx.x*128 + (t >> 1);
  int sg = t & 1;           // channel-half owner
  int jb = sg*16;           // own output-channel base

  // --- proj both streams for own 16 channels (shared wp reads)
  float A[16], B[16];
#pragma unroll
  for (int jj = 0; jj < 16; jj++) { A[jj] = bps[jb+jj]; B[jj] = A[jj]; }
#pragma unroll
  for (int c = 0; c < 32; c++) {
    float va = ao1[c*HW+p];
    float vb = ao2[c*HW+p];
    const float4* w4 = (const float4*)&wps[c*32 + jb];
#pragma unroll
    for (int j4 = 0; j4 < 4; j4++) {
      float4 w = w4[j4];
      A[j4*4+0] += va*w.x; A[j4*4+1] += va*w.y; A[j4*4+2] += va*w.z; A[j4*4+3] += va*w.w;
      B[j4*4+0] += vb*w.x; B[j4*4+1] += vb*w.y; B[j4*4+2] += vb*w.z; B[j4*4+3] += vb*w.w;
    }
  }
  // --- shortcuts + OUT init (own channels)
  float OUT[16];
#pragma unroll
  for (int jj = 0; jj < 16; jj++) {
    float xv = x[(jb+jj)*HW+p];
    float tv = t4[(jb+jj)*HW+p]*as_[jb+jj] + bbs_[jb+jj];
    A[jj] += xv; B[jj] += tv;
    OUT[jj] = A[jj] + B[jj] + xv + 2.f*b2s[jb+jj];
  }
  // --- LN stats via lane-pair reduce
  float sA = 0.f, sB = 0.f;
#pragma unroll
  for (int jj = 0; jj < 16; jj++) { sA += A[jj]; sB += B[jj]; }
  sA += __shfl_xor(sA, 1, 64);
  sB += __shfl_xor(sB, 1, 64);
  float mA = sA * 0.03125f, mB = sB * 0.03125f;
  float ssA = 0.f, ssB = 0.f;
#pragma unroll
  for (int jj = 0; jj < 16; jj++) {
    float dA = A[jj]-mA, dB = B[jj]-mB;
    ssA += dA*dA; ssB += dB*dB;
  }
  ssA += __shfl_xor(ssA, 1, 64);
  ssB += __shfl_xor(ssB, 1, 64);
  float rsA = rsqrtf(ssA*0.03125f + 1e-5f);
  float rsB = rsqrtf(ssB*0.03125f + 1e-5f);
  // --- ln own + pair exchange -> full 32 per stream (static-indexed halves)
  float lnA_lo[16], lnA_hi[16], lnB_lo[16], lnB_hi[16];
#pragma unroll
  for (int jj = 0; jj < 16; jj++) {
    float ownA = (A[jj]-mA)*rsA*gs[jb+jj] + bs[jb+jj];
    float ownB = (B[jj]-mB)*rsB*gs[jb+jj] + bs[jb+jj];
    float othA = __shfl_xor(ownA, 1, 64);
    float othB = __shfl_xor(ownB, 1, 64);
    lnA_lo[jj] = sg ? othA : ownA;
    lnA_hi[jj] = sg ? ownA : othA;
    lnB_lo[jj] = sg ? othB : ownB;
    lnB_hi[jj] = sg ? ownB : othB;
  }
  // --- mlp1: own 32 of 64 hidden (k = sg*32+kk), both streams share w1 reads
  float h0[32], h1[32];
#pragma unroll
  for (int kk = 0; kk < 32; kk++) { h0[kk] = b1s[sg*32+kk]; h1[kk] = h0[kk]; }
#pragma unroll
  for (int c = 0; c < 32; c++) {
    float l0 = (c < 16) ? lnA_lo[c] : lnA_hi[c-16];
    float l1 = (c < 16) ? lnB_lo[c] : lnB_hi[c-16];
    const float4* w4 = (const float4*)&w1s[c*64 + sg*32];
#pragma unroll
    for (int k4 = 0; k4 < 8; k4++) {
      float4 w = w4[k4];
      h0[k4*4+0] += l0*w.x; h0[k4*4+1] += l0*w.y; h0[k4*4+2] += l0*w.z; h0[k4*4+3] += l0*w.w;
      h1[k4*4+0] += l1*w.x; h1[k4*4+1] += l1*w.y; h1[k4*4+2] += l1*w.z; h1[k4*4+3] += l1*w.w;
    }
  }
  // --- gelu, then g = gelu(h0)+gelu(h1) (mlp2 is linear: r0+r1 = mlp2(g))
#pragma unroll
  for (int kk = 0; kk < 32; kk++) {
    float x0 = h0[kk], x1 = h1[kk];
    float u0 = 0.7978845608f * (x0 + 0.044715f*x0*x0*x0);
    float u1 = 0.7978845608f * (x1 + 0.044715f*x1*x1*x1);
    float th0 = 1.f - 2.f/(1.f + __expf(2.f*u0));
    float th1 = 1.f - 2.f/(1.f + __expf(2.f*u1));
    h0[kk] = 0.5f*x0*(1.f + th0) + 0.5f*x1*(1.f + th1);
  }
  // --- mlp2 partials over own k-half, for ALL 32 j (two static halves)
  float plo[16], phi[16];
#pragma unroll
  for (int jj = 0; jj < 16; jj++) { plo[jj] = 0.f; phi[jj] = 0.f; }
#pragma unroll
  for (int kk = 0; kk < 32; kk++) {
    float gk = h0[kk];
    const float4* w4 = (const float4*)&w2s[(sg*32+kk)*32];
#pragma unroll
    for (int j4 = 0; j4 < 4; j4++) {
      float4 w = w4[j4];
      plo[j4*4+0] += gk*w.x; plo[j4*4+1] += gk*w.y;
      plo[j4*4+2] += gk*w.z; plo[j4*4+3] += gk*w.w;
    }
#pragma unroll
    for (int j4 = 0; j4 < 4; j4++) {
      float4 w = w4[4+j4];
      phi[j4*4+0] += gk*w.x; phi[j4*4+1] += gk*w.y;
      phi[j4*4+2] += gk*w.z; phi[j4*4+3] += gk*w.w;
    }
  }
  // --- pair exchange of cross-half partials, accumulate, store
#pragma unroll
  for (int jj = 0; jj < 16; jj++) {
    float send = sg ? plo[jj] : phi[jj];    // what partner needs
    float recv = __shfl_xor(send, 1, 64);   // partner's partial at my j
    float own  = sg ? phi[jj] : plo[jj];
    out[(jb+jj)*HW + p] = OUT[jj] + own + recv;
  }
}

extern "C" void kernel_launch(void* const* d_in, const int* in_sizes, int n_in,
                              void* d_out, int out_size, void* d_ws, size_t ws_size,
                              hipStream_t stream) {
  const float* x    = (const float*)d_in[0];
  const float* depth= (const float*)d_in[1];
  const int*   rpi  = (const int*)d_in[2];
  const float* cw1  = (const float*)d_in[3],  *cb1 = (const float*)d_in[4];
  const float* cw2  = (const float*)d_in[5],  *cb2 = (const float*)d_in[6];
  const float* cw3  = (const float*)d_in[7],  *cb3 = (const float*)d_in[8];
  const float* cw4  = (const float*)d_in[9],  *cb4 = (const float*)d_in[10];
  const float* in_g = (const float*)d_in[11], *in_b = (const float*)d_in[12];
  const float* n1g  = (const float*)d_in[13], *n1b = (const float*)d_in[14];
  const float* wq   = (const float*)d_in[15], *bq  = (const float*)d_in[16];
  const float* wkv  = (const float*)d_in[17], *bkv = (const float*)d_in[18];
  const float* rpb  = (const float*)d_in[19];
  const float* wp   = (const float*)d_in[20], *bp  = (const float*)d_in[21];
  const float* n2g  = (const float*)d_in[22], *n2b = (const float*)d_in[23];
  const float* mw1  = (const float*)d_in[24], *mb1 = (const float*)d_in[25];
  const float* mw2  = (const float*)d_in[26], *mb2 = (const float*)d_in[27];

  float* W   = (float*)d_ws;
  float* o1  = (float*)d_out;

  // workspace layout (floats), total 12878848 = 51.5 MB
  float* t4    = W;                          // 2M
  unsigned int* q1  = (unsigned int*)(W + 2097152);   // 1M words
  unsigned int* q2  = (unsigned int*)(W + 3145728);   // 1M words
  unsigned int* kv1 = (unsigned int*)(W + 4194304);   // 2M words
  unsigned int* kv2 = (unsigned int*)(W + 6291456);   // 2M words
  float* ao1   = W + 8388608;                // 2M
  float* ao2   = W + 10485760;               // 2M
  unsigned int* biasPk = (unsigned int*)(W + 12582912);  // 147456 words
  float* part  = W + 12877824;               // 1024
  float* t2 = ao1;                           // 1M used, dead before attn writes ao1
  float* t3 = ao2;                           // 1M used, dead before attn writes ao2

  // flat misc: stem(256) + biasPk(576) + lnmm48 roles 0,1 (512) = 1344 blocks
  k_misc   <<<1344, 256, 0, stream>>>(depth, cw1, cb1, cw2, cb2, t2,
                                      rpi, rpb, biasPk,
                                      x, t4, part, in_g, in_b, n1g, n1b,
                                      wq, bq, wkv, bkv, q1, kv1, q2, kv2);
  k_conv3  <<<dim3(256,4), 256, 0, stream>>>(t2, cw3, cb3, t3);
  k_conv4  <<<dim3(256,4), 256, 0, stream>>>(t3, cw4, cb4, t4);
  k_instats1<<<512, 256, 0, stream>>>(t4, part);
  // roles 2,3: src=IN(t4) -> q2, kv1
  k_lnmmB  <<<dim3(256,2), 256, 0, stream>>>(x, t4, part, in_g, in_b, n1g, n1b,
                                             wq, bq, wkv, bkv, q1, kv1, q2, kv2);
  k_attn   <<<dim3(512,2), 256, 0, stream>>>(q1, kv1, ao1, q2, kv2, ao2, biasPk);
  k_projmlp<<<512, 256, 0, stream>>>(ao1, ao2, x, t4, part, in_g, in_b,
                                     wp, bp, n2g, n2b, mw1, mb1, mw2, mb2, o1);
}